// Round 14
// baseline (274.939 us; speedup 1.0000x reference)
//
#include <hip/hip_runtime.h>
#include <math.h>

#define NPTS 65536

using half8   = __attribute__((ext_vector_type(8))) _Float16;
using half4   = __attribute__((ext_vector_type(4))) _Float16;
using floatx4 = __attribute__((ext_vector_type(4))) float;

// ---------------------------------------------------------------------------
// k_prep: weights -> f16 in GEMM-COALESCED layout:
//   element (d, kc) at [((w*4+p)*8 + k2)*512 + mm*32 + (kc&31)]
//   where d = w*16+mm, kc = p*256 + k2*32 + (kc&31).
//   A wave (fixed w,p,k2) reads one contiguous 1KB line per k-step (r12 win:
//   k_fused 201->173us vs the old d-major scatter).
// features -> f16 table featH[N][64]. Block 0 also zeroes stats.
// ---------------------------------------------------------------------------
__global__ __launch_bounds__(256) void k_prep(
    const float* __restrict__ ow, const float* __restrict__ w,
    const float* __restrict__ feat,
    _Float16* __restrict__ owt, _Float16* __restrict__ wt,
    _Float16* __restrict__ featH, float* __restrict__ stats)
{
  int b = blockIdx.x;
  if (b < 64) {                        // 2 matrices x (4 kc-chunks x 8 d-chunks)
    __shared__ float tile[256][9];     // pad 9: conflict-free both passes
    int mat = b >> 5, bb = b & 31;
    int kcb = bb & 3, db = bb >> 2;    // kcb == p (quarter), db = d-chunk of 8
    int t = threadIdx.x;
    int kc = kcb * 256 + t;
    int c = kc >> 4, k = kc & 15;
    const float* src = mat ? w : ow;
    int dmax = mat ? 64 : 60;
    #pragma unroll
    for (int di = 0; di < 8; ++di) {
      int d = db * 8 + di;
      float v = 0.f;
      if (k < 15 && d < dmax) v = src[(k * 64 + c) * dmax + d];
      tile[t][di] = v;
    }
    __syncthreads();
    _Float16* dst = mat ? wt : owt;
    int k2 = t >> 5, lo = t & 31;      // k-step, within-32 offset
    #pragma unroll
    for (int di = 0; di < 8; ++di) {   // 64B-run writes
      int d = db * 8 + di;
      int wv = d >> 4, mm = d & 15;
      dst[((wv * 4 + kcb) * 8 + k2) * 512 + mm * 32 + lo] = (_Float16)tile[t][di];
    }
    if (b == 0 && t < 128) stats[t] = 0.f;
  } else {                             // 4096*256 == 1048576 == N*64/4
    int j = (b - 64) * 256 + threadIdx.x;
    float4 f = ((const float4*)feat)[j];
    half4 h = {(_Float16)f.x, (_Float16)f.y, (_Float16)f.z, (_Float16)f.w};
    ((half4*)featH)[j] = h;
  }
}

// ---------------------------------------------------------------------------
// Fused deformable KPConv. 16 pts/block, 4 waves x 4 pts. Round-13 base
// with ONE delta: np staged as FOUR SEPARATE f32 arrays (npx/y/z/w) instead
// of float4. Same arithmetic (dot-form d2 = w + hk - 2 np.kp, bit-exact),
// but 4 scalar ds_read_b32 instead of one ds_read_b128: b128 LDS loads
// force quad-aligned 4-VGPR tuples, which at the hard 64-reg (256,4) cap
// fragmented the allocator -> r13's 50MB scratch spill (WRITE 22.5->67.6MB)
// that ate the VALU win. Tripwire: WRITE must return to ~22MB.
// Frozen: coalesced-B GEMM + setprio (r12/13), swap03 transpose swizzle
// (r11), chained rank-2 MFMA + modme fold, quarter-K phasing, dkh f16,
// fused stats, (256,4). Closed: bank conflicts, tr_read path.
// LDS 40640 B -> 4 blocks/CU.
// ---------------------------------------------------------------------------
__global__ __launch_bounds__(256, 4) void k_fused(
    const float* __restrict__ query, const float* __restrict__ support,
    const int* __restrict__ nidx, const _Float16* __restrict__ featH,
    const float* __restrict__ kpts, const float* __restrict__ obias,
    const _Float16* __restrict__ owt, const _Float16* __restrict__ wt,
    float* __restrict__ outx, float* __restrict__ stats)
{
  __shared__ float                  npx[16][34], npy[16][34];
  __shared__ float                  npz[16][34], npw[16][34];  // 8704B
  __shared__ unsigned short         sidx[16][34];    // 1088B
  __shared__ __align__(16) _Float16 fT[4][64 * 32];  // per-wave transpose 16384B
  __shared__ unsigned int           fx2s[16][64];    // (f32,f33) per pt,c 4096B
  __shared__ __align__(16) _Float16 wfh[16 * 264];   // quarter-K A-panel 8448B
  __shared__ _Float16               dkh[16][60];     // def_kp(45)+mod(15) 1920B

  const int tid  = threadIdx.x;
  const int wave = tid >> 6, lane = tid & 63;
  const int quad = lane >> 4, mm = lane & 15;
  const int base = blockIdx.x * 16;
  _Float16* fTw = fT[wave];
  unsigned int* fTw32 = (unsigned int*)fTw;
  const floatx4 fz = {0.f, 0.f, 0.f, 0.f};
  const int me = (mm < 15) ? mm : 14;   // row 15 of conv A is discarded
  // swap bits 0<->3 of mm: channel this lane computes within each quarter
  const int mmw = (mm & 6) | ((mm & 1) << 3) | ((mm >> 3) & 1);

  // ---- stage neighbor displacements (+|np|^2) + indices ----
  for (int s = tid; s < 544; s += 256) {
    int pt = s / 34, a = s - pt * 34;
    int n = base + pt;
    int id = nidx[n * 34 + a];
    float dx = support[id * 3 + 0] - query[n * 3 + 0];
    float dy = support[id * 3 + 1] - query[n * 3 + 1];
    float dz = support[id * 3 + 2] - query[n * 3 + 2];
    npx[pt][a] = dx; npy[pt][a] = dy; npz[pt][a] = dz;
    npw[pt][a] = dx * dx + dy * dy + dz * dz;
    sidx[pt][a] = (unsigned short)id;
  }
  __syncthreads();

  // ---- rank-2 neighbor (rows 32,33) features -> fx2s[pt][c], once/block ----
  if (tid < 128) {
    int pt = tid >> 3, ch = tid & 7;
    int i0 = (int)sidx[pt][32], i1 = (int)sidx[pt][33];
    uint4 g0 = *(const uint4*)(featH + i0 * 64 + ch * 8);
    uint4 g1 = *(const uint4*)(featH + i1 * 64 + ch * 8);
    const uint* p0 = (const uint*)&g0;
    const uint* p1 = (const uint*)&g1;
    #pragma unroll
    for (int cc = 0; cc < 8; ++cc) {
      uint v = __builtin_amdgcn_perm(p1[cc >> 1], p0[cc >> 1],
                                     (cc & 1) ? 0x07060302u : 0x05040100u);
      fx2s[pt][ch * 8 + cc] = v;
    }
  }
  __syncthreads();

  // ---- gather loads: 16 row-pairs x 8 chunks = 128 tasks, 2 full iters ----
  auto load_g = [&](int pl, uint4* g0, uint4* g1) {
    #pragma unroll
    for (int it = 0; it < 2; ++it) {
      int task = it * 64 + lane;
      int rp = task >> 3, ch = task & 7;
      int i0 = (int)sidx[pl][2 * rp], i1 = (int)sidx[pl][2 * rp + 1];
      g0[it] = *(const uint4*)(featH + i0 * 64 + ch * 8);
      g1[it] = *(const uint4*)(featH + i1 * 64 + ch * 8);
    }
  };
  // ---- transpose staged regs -> fTw at swizzled row fc = swap03(c) ----
  auto transpose_g = [&](const uint4* g0, const uint4* g1) {
    #pragma unroll
    for (int it = 0; it < 2; ++it) {
      int task = it * 64 + lane;
      int rp = task >> 3, ch = task & 7;
      int chunk = rp >> 2, o = rp & 3;
      const uint* p0 = (const uint*)&g0[it];
      const uint* p1 = (const uint*)&g1[it];
      #pragma unroll
      for (int cc = 0; cc < 8; ++cc) {
        int c  = ch * 8 + cc;
        int fc = (c & 0x36) | ((c & 1) << 3) | ((c >> 3) & 1);
        int pc = chunk ^ ((ch ^ cc) & 3);     // salt keyed by TRUE c
        uint v = __builtin_amdgcn_perm(p1[cc >> 1], p0[cc >> 1],
                                       (cc & 1) ? 0x07060302u : 0x05040100u);
        fTw32[fc * 16 + pc * 4 + o] = v;
      }
    }
  };

  // ---- one conv point: 4x (MFMA nbr0..31 + chained rank-2 MFMA nbr32,33).
  //      dot-form influence: d2 = |np|^2 + |kp|^2 - 2 np.kp (4 b32 reads).
  //      modulation pre-folded into A rows (lane row == kernel point).
  //      writes ct0 quarter to wfh, returns ct1..3 packed in hq3[3] ----
  auto conv_point = [&](int pl, float kx, float ky, float kz, float modme,
                        half4* hq3) {
    float hk = kx * kx + ky * ky + kz * kz;
    half8 a0;
    #pragma unroll
    for (int j = 0; j < 8; ++j) {
      int a = quad * 8 + j;
      float px = npx[pl][a], py = npy[pl][a], pz = npz[pl][a], pw = npw[pl][a];
      float dt = px * kx + py * ky + pz * kz;
      float d2 = fmaxf(pw + hk - 2.f * dt, 0.f);
      a0[j] = (_Float16)(fmaxf(1.f - 2.f * sqrtf(d2), 0.f) * modme);
    }
    // rank-2 rows: virtual k'=0,1 supplied only by quad-0 lanes (row = mm)
    float dt32 = npx[pl][32] * kx + npy[pl][32] * ky + npz[pl][32] * kz;
    float w32 = fmaxf(1.f - 2.f * sqrtf(fmaxf(npw[pl][32] + hk - 2.f * dt32, 0.f)),
                      0.f) * modme;
    float dt33 = npx[pl][33] * kx + npy[pl][33] * ky + npz[pl][33] * kz;
    float w33 = fmaxf(1.f - 2.f * sqrtf(fmaxf(npw[pl][33] + hk - 2.f * dt33, 0.f)),
                      0.f) * modme;
    half8 a2 = {};
    a2[0] = (_Float16)((quad == 0) ? w32 : 0.f);
    a2[1] = (_Float16)((quad == 0) ? w33 : 0.f);
    #pragma unroll
    for (int ct = 0; ct < 4; ++ct) {
      int c  = ct * 16 + mmw;                 // true channel
      int pc = quad ^ (((c >> 3) ^ c) & 3);
      half8 b = *(const half8*)(fTw + (ct * 16 + mm) * 32 + pc * 8);
      floatx4 acc = __builtin_amdgcn_mfma_f32_16x16x32_f16(a0, b, fz, 0, 0, 0);
      uint fp = fx2s[pl][c];
      half8 b2 = {};
      b2[0] = __builtin_bit_cast(_Float16, (unsigned short)(fp & 0xffffu));
      b2[1] = __builtin_bit_cast(_Float16, (unsigned short)(fp >> 16));
      acc = __builtin_amdgcn_mfma_f32_16x16x32_f16(a2, b2, acc, 0, 0, 0);
      half4 h = {(_Float16)acc[0], (_Float16)acc[1],
                 (_Float16)acc[2], (_Float16)acc[3]};
      if (ct == 0) *(half4*)(wfh + pl * 264 + mmw * 16 + quad * 4) = h;
      else         hq3[ct - 1] = h;
    }
  };

  // ---- write one held quarter (ct = idx+1) into wfh (row = mmw) ----
  auto write_hold = [&](const half4 (*hq)[3], int idx) {
    #pragma unroll
    for (int pp = 0; pp < 4; ++pp)
      *(half4*)(wfh + (wave * 4 + pp) * 264 + mmw * 16 + quad * 4) = hq[pp][idx];
  };

  // ---- quarter-K GEMM: 8 k-steps; coalesced B (1KB wave-load per k-step);
  //      setprio(1) keeps the MFMA burst fed (T5, independent-block regime) ----
  auto gemm_q = [&](const _Float16* bmat, int p, floatx4& A, floatx4& B) {
    const _Float16* brow = bmat + ((wave * 4 + p) * 8) * 512 + mm * 32 + quad * 8;
    const _Float16* arow = wfh + mm * 264;
    __builtin_amdgcn_s_setprio(1);
    #pragma unroll
    for (int k2 = 0; k2 < 8; ++k2) {
      half8 af = *(const half8*)(arow + k2 * 32 + quad * 8);
      half8 bf = *(const half8*)(brow + k2 * 512);
      if (k2 & 1) B = __builtin_amdgcn_mfma_f32_16x16x32_f16(af, bf, B, 0, 0, 0);
      else        A = __builtin_amdgcn_mfma_f32_16x16x32_f16(af, bf, A, 0, 0, 0);
    }
    __builtin_amdgcn_s_setprio(0);
  };

  uint4 G0[2], G1[2];       // single gather buffer (16 VGPRs)
  half4 hq[4][3];           // deferred quarters, packed f16 (12 VGPRs)
  const float k0x = kpts[me * 3 + 0], k0y = kpts[me * 3 + 1], k0z = kpts[me * 3 + 2];

  // ================= conv0 (rigid kernel points) =================
  {
    load_g(wave * 4, G0, G1);
    #pragma unroll
    for (int pp = 0; pp < 4; ++pp) {
      int pl = wave * 4 + pp;
      transpose_g(G0, G1);
      if (pp < 3) load_g(pl + 1, G0, G1);   // issue next gather; conv covers it
      conv_point(pl, k0x, k0y, k0z, 1.f, hq[pp]);
    }
  }
  load_g(wave * 4, G0, G1);   // prefetch conv1 p0 under GEMM0
  __syncthreads();

  // ================= GEMM0 (4 quarter phases) -> def_kp + modulations ========
  {
    floatx4 A = fz, B = fz;
    gemm_q(owt, 0, A, B);
    __syncthreads(); write_hold(hq, 0); __syncthreads();
    gemm_q(owt, 1, A, B);
    __syncthreads(); write_hold(hq, 1); __syncthreads();
    gemm_q(owt, 2, A, B);
    __syncthreads(); write_hold(hq, 2); __syncthreads();
    gemm_q(owt, 3, A, B);
    int d = wave * 16 + mm;
    float bv = (d < 60) ? obias[d] : 0.f;
    float kv = (d < 45) ? kpts[d] : 0.f;
    #pragma unroll
    for (int r = 0; r < 4; ++r) {
      int pt = quad * 4 + r;
      float v = A[r] + B[r] + bv;
      if (d < 60)
        dkh[pt][d] = (_Float16)((d < 45) ? (kv + 0.5f * v)        // kp + f0*EXTENT
                                         : (2.f / (1.f + expf(-v))));  // modulation
    }
  }
  __syncthreads();   // dkh ready; GEMM0 wfh reads done

  // ================= conv1 (deformed kernel points) =================
  #pragma unroll
  for (int pp = 0; pp < 4; ++pp) {
    int pl = wave * 4 + pp;
    float kx = (float)dkh[pl][me * 3 + 0];
    float ky = (float)dkh[pl][me * 3 + 1];
    float kz = (float)dkh[pl][me * 3 + 2];
    float modme = (float)dkh[pl][45 + me];
    transpose_g(G0, G1);
    if (pp < 3) load_g(pl + 1, G0, G1);
    conv_point(pl, kx, ky, kz, modme, hq[pp]);
  }
  __syncthreads();

  // ================= GEMM1 (4 quarter phases) -> x + fused batch stats =======
  {
    floatx4 A = fz, B = fz;
    gemm_q(wt, 0, A, B);
    __syncthreads(); write_hold(hq, 0); __syncthreads();
    gemm_q(wt, 1, A, B);
    __syncthreads(); write_hold(hq, 1); __syncthreads();
    gemm_q(wt, 2, A, B);
    __syncthreads(); write_hold(hq, 2); __syncthreads();
    gemm_q(wt, 3, A, B);
    int d = wave * 16 + mm;
    float s1 = 0.f, s2 = 0.f;
    #pragma unroll
    for (int r = 0; r < 4; ++r) {
      float v = A[r] + B[r];
      outx[(base + quad * 4 + r) * 64 + d] = v;
      s1 += v; s2 += v * v;
    }
    s1 += __shfl_xor(s1, 16); s2 += __shfl_xor(s2, 16);
    s1 += __shfl_xor(s1, 32); s2 += __shfl_xor(s2, 32);
    if (lane < 16) {
      atomicAdd(&stats[d], s1);
      atomicAdd(&stats[64 + d], s2);
    }
  }
}

// ---------------------------------------------------------------------------
// BN (batch stats, biased var, eps=1e-6) + LeakyReLU(0.1), in-place
// ---------------------------------------------------------------------------
__global__ __launch_bounds__(256) void k_norm(
    float* __restrict__ x, const float* __restrict__ stats,
    const float* __restrict__ gamma, const float* __restrict__ beta)
{
  const int i = blockIdx.x * 256 + threadIdx.x;
  float4 v = ((float4*)x)[i];
  const int c0 = (i * 4) & 63;
  float o[4] = {v.x, v.y, v.z, v.w};
  #pragma unroll
  for (int j = 0; j < 4; ++j) {
    int c = c0 + j;
    float mean = stats[c] * (1.f / NPTS);
    float var  = stats[64 + c] * (1.f / NPTS) - mean * mean;
    float s = rsqrtf(var + 1e-6f) * gamma[c];
    float y = (o[j] - mean) * s + beta[c];
    o[j] = (y >= 0.f) ? y : 0.1f * y;
  }
  float4 rv = {o[0], o[1], o[2], o[3]};
  ((float4*)x)[i] = rv;
}

// ---------------------------------------------------------------------------
extern "C" void kernel_launch(void* const* d_in, const int* in_sizes, int n_in,
                              void* d_out, int out_size, void* d_ws, size_t ws_size,
                              hipStream_t stream)
{
  const float* query   = (const float*)d_in[0];
  const float* support = (const float*)d_in[1];
  const int*   nidx    = (const int*)d_in[2];
  const float* feat    = (const float*)d_in[3];
  const float* weight  = (const float*)d_in[4];
  const float* oweight = (const float*)d_in[5];
  const float* obias   = (const float*)d_in[6];
  const float* gamma   = (const float*)d_in[7];
  const float* beta    = (const float*)d_in[8];
  const float* kpts    = (const float*)d_in[9];
  float* x = (float*)d_out;

  char* ws = (char*)d_ws;
  _Float16* featH = (_Float16*)ws;                  // 8,388,608 B
  _Float16* owt   = (_Float16*)(ws + 8388608);      //   131,072 B
  _Float16* wt    = (_Float16*)(ws + 8519680);      //   131,072 B
  float*    stats = (float*)(ws + 8650752);         //       512 B

  k_prep<<<4160, 256, 0, stream>>>(oweight, weight, feat, owt, wt, featH, stats);
  k_fused<<<4096, 256, 0, stream>>>(query, support, nidx, featH, kpts, obias,
                                    owt, wt, x, stats);
  k_norm<<<4096, 256, 0, stream>>>(x, stats, gamma, beta);
}

// Round 15
// 249.713 us; speedup vs baseline: 1.1010x; 1.1010x over previous
//
#include <hip/hip_runtime.h>
#include <math.h>

#define NPTS 65536

using half8   = __attribute__((ext_vector_type(8))) _Float16;
using half4   = __attribute__((ext_vector_type(4))) _Float16;
using floatx4 = __attribute__((ext_vector_type(4))) float;

// ---------------------------------------------------------------------------
// k_prep: weights -> f16 in GEMM-COALESCED layout:
//   element (d, kc) at [((w*4+p)*8 + k2)*512 + mm*32 + (kc&31)]
//   where d = w*16+mm, kc = p*256 + k2*32 + (kc&31).
//   A wave (fixed w,p,k2) reads one contiguous 1KB line per k-step (r12 win:
//   k_fused 201->173us vs the old d-major scatter).
// features -> f16 table featH[N][64]. Block 0 also zeroes stats.
// ---------------------------------------------------------------------------
__global__ __launch_bounds__(256) void k_prep(
    const float* __restrict__ ow, const float* __restrict__ w,
    const float* __restrict__ feat,
    _Float16* __restrict__ owt, _Float16* __restrict__ wt,
    _Float16* __restrict__ featH, float* __restrict__ stats)
{
  int b = blockIdx.x;
  if (b < 64) {                        // 2 matrices x (4 kc-chunks x 8 d-chunks)
    __shared__ float tile[256][9];     // pad 9: conflict-free both passes
    int mat = b >> 5, bb = b & 31;
    int kcb = bb & 3, db = bb >> 2;    // kcb == p (quarter), db = d-chunk of 8
    int t = threadIdx.x;
    int kc = kcb * 256 + t;
    int c = kc >> 4, k = kc & 15;
    const float* src = mat ? w : ow;
    int dmax = mat ? 64 : 60;
    #pragma unroll
    for (int di = 0; di < 8; ++di) {
      int d = db * 8 + di;
      float v = 0.f;
      if (k < 15 && d < dmax) v = src[(k * 64 + c) * dmax + d];
      tile[t][di] = v;
    }
    __syncthreads();
    _Float16* dst = mat ? wt : owt;
    int k2 = t >> 5, lo = t & 31;      // k-step, within-32 offset
    #pragma unroll
    for (int di = 0; di < 8; ++di) {   // 64B-run writes
      int d = db * 8 + di;
      int wv = d >> 4, mm = d & 15;
      dst[((wv * 4 + kcb) * 8 + k2) * 512 + mm * 32 + lo] = (_Float16)tile[t][di];
    }
    if (b == 0 && t < 128) stats[t] = 0.f;
  } else {                             // 4096*256 == 1048576 == N*64/4
    int j = (b - 64) * 256 + threadIdx.x;
    float4 f = ((const float4*)feat)[j];
    half4 h = {(_Float16)f.x, (_Float16)f.y, (_Float16)f.z, (_Float16)f.w};
    ((half4*)featH)[j] = h;
  }
}

// ---------------------------------------------------------------------------
// Fused deformable KPConv. 16 pts/block, 4 waves x 4 pts. EXACT round-12
// base (passing, 173us k_fused, WRITE 22.5MB no-spill) + ONE register-
// neutral delta: s_setprio(1/0) around the GEMM MFMA bursts (T5; SALU only).
// Dot-form influence is permanently CLOSED: r13 (float4, +50MB spill) and
// r14 (4 scalar arrays, +94MB spill) both showed its 4-loads/neighbor
// batched live-set tips the hard 64-reg (256,4) budget into scratch; its
// ~16 VALU/pt saving cannot pay for any spill. Subtract-form (3 loads) is
// the proven fit. Also closed: bank conflicts (counter pinned 1.69e7,
// uncorrelated), tr_read/global_load_lds (2 deterministic failures).
// LDS 40448 B -> 4 blocks/CU, VGPR 64.
// ---------------------------------------------------------------------------
__global__ __launch_bounds__(256, 4) void k_fused(
    const float* __restrict__ query, const float* __restrict__ support,
    const int* __restrict__ nidx, const _Float16* __restrict__ featH,
    const float* __restrict__ kpts, const float* __restrict__ obias,
    const _Float16* __restrict__ owt, const _Float16* __restrict__ wt,
    float* __restrict__ outx, float* __restrict__ stats)
{
  __shared__ float                  npx[16][34], npy[16][34], npz[16][34]; // 6528B
  __shared__ unsigned short         sidx[16][34];    // 1088B
  __shared__ __align__(16) _Float16 fT[4][64 * 32];  // per-wave transpose 16384B
  __shared__ unsigned int           fx2s[16][64];    // (f32,f33) per pt,c 4096B
  __shared__ __align__(16) _Float16 wfh[16 * 264];   // quarter-K A-panel 8448B
  __shared__ float                  dk[16][60];      // def_kp(45)+mod(15) 3840B

  const int tid  = threadIdx.x;
  const int wave = tid >> 6, lane = tid & 63;
  const int quad = lane >> 4, mm = lane & 15;
  const int base = blockIdx.x * 16;
  _Float16* fTw = fT[wave];
  unsigned int* fTw32 = (unsigned int*)fTw;
  const floatx4 fz = {0.f, 0.f, 0.f, 0.f};
  const int me = (mm < 15) ? mm : 14;   // row 15 of conv A is discarded
  // swap bits 0<->3 of mm: channel this lane computes within each quarter
  const int mmw = (mm & 6) | ((mm & 1) << 3) | ((mm >> 3) & 1);

  // ---- stage neighbor displacements + indices ----
  for (int s = tid; s < 544; s += 256) {
    int pt = s / 34, a = s - pt * 34;
    int n = base + pt;
    int id = nidx[n * 34 + a];
    npx[pt][a] = support[id * 3 + 0] - query[n * 3 + 0];
    npy[pt][a] = support[id * 3 + 1] - query[n * 3 + 1];
    npz[pt][a] = support[id * 3 + 2] - query[n * 3 + 2];
    sidx[pt][a] = (unsigned short)id;
  }
  __syncthreads();

  // ---- rank-2 neighbor (rows 32,33) features -> fx2s[pt][c], once/block ----
  if (tid < 128) {
    int pt = tid >> 3, ch = tid & 7;
    int i0 = (int)sidx[pt][32], i1 = (int)sidx[pt][33];
    uint4 g0 = *(const uint4*)(featH + i0 * 64 + ch * 8);
    uint4 g1 = *(const uint4*)(featH + i1 * 64 + ch * 8);
    const uint* p0 = (const uint*)&g0;
    const uint* p1 = (const uint*)&g1;
    #pragma unroll
    for (int cc = 0; cc < 8; ++cc) {
      uint v = __builtin_amdgcn_perm(p1[cc >> 1], p0[cc >> 1],
                                     (cc & 1) ? 0x07060302u : 0x05040100u);
      fx2s[pt][ch * 8 + cc] = v;
    }
  }
  __syncthreads();

  // ---- gather loads: 16 row-pairs x 8 chunks = 128 tasks, 2 full iters ----
  auto load_g = [&](int pl, uint4* g0, uint4* g1) {
    #pragma unroll
    for (int it = 0; it < 2; ++it) {
      int task = it * 64 + lane;
      int rp = task >> 3, ch = task & 7;
      int i0 = (int)sidx[pl][2 * rp], i1 = (int)sidx[pl][2 * rp + 1];
      g0[it] = *(const uint4*)(featH + i0 * 64 + ch * 8);
      g1[it] = *(const uint4*)(featH + i1 * 64 + ch * 8);
    }
  };
  // ---- transpose staged regs -> fTw at swizzled row fc = swap03(c) ----
  auto transpose_g = [&](const uint4* g0, const uint4* g1) {
    #pragma unroll
    for (int it = 0; it < 2; ++it) {
      int task = it * 64 + lane;
      int rp = task >> 3, ch = task & 7;
      int chunk = rp >> 2, o = rp & 3;
      const uint* p0 = (const uint*)&g0[it];
      const uint* p1 = (const uint*)&g1[it];
      #pragma unroll
      for (int cc = 0; cc < 8; ++cc) {
        int c  = ch * 8 + cc;
        int fc = (c & 0x36) | ((c & 1) << 3) | ((c >> 3) & 1);
        int pc = chunk ^ ((ch ^ cc) & 3);     // salt keyed by TRUE c
        uint v = __builtin_amdgcn_perm(p1[cc >> 1], p0[cc >> 1],
                                       (cc & 1) ? 0x07060302u : 0x05040100u);
        fTw32[fc * 16 + pc * 4 + o] = v;
      }
    }
  };

  // ---- one conv point: 4x (MFMA nbr0..31 + chained rank-2 MFMA nbr32,33).
  //      lane's channel within quarter ct is c = ct*16+mmw (stored at row
  //      ct*16+mm). modulation pre-folded into A rows (lane row == kp).
  //      writes ct0 quarter to wfh, returns ct1..3 packed in hq3[3] ----
  auto conv_point = [&](int pl, float kx, float ky, float kz, float modme,
                        half4* hq3) {
    half8 a0;
    #pragma unroll
    for (int j = 0; j < 8; ++j) {
      int a = quad * 8 + j;
      float dx = npx[pl][a] - kx, dy = npy[pl][a] - ky, dz = npz[pl][a] - kz;
      float wv = 1.f - 2.f * sqrtf(dx * dx + dy * dy + dz * dz);
      a0[j] = (_Float16)(fmaxf(wv, 0.f) * modme);
    }
    // rank-2 rows: virtual k'=0,1 supplied only by quad-0 lanes (row = mm)
    float dx = npx[pl][32] - kx, dy = npy[pl][32] - ky, dz = npz[pl][32] - kz;
    float w32 = fmaxf(1.f - 2.f * sqrtf(dx * dx + dy * dy + dz * dz), 0.f) * modme;
    dx = npx[pl][33] - kx; dy = npy[pl][33] - ky; dz = npz[pl][33] - kz;
    float w33 = fmaxf(1.f - 2.f * sqrtf(dx * dx + dy * dy + dz * dz), 0.f) * modme;
    half8 a2 = {};
    a2[0] = (_Float16)((quad == 0) ? w32 : 0.f);
    a2[1] = (_Float16)((quad == 0) ? w33 : 0.f);
    #pragma unroll
    for (int ct = 0; ct < 4; ++ct) {
      int c  = ct * 16 + mmw;                 // true channel
      int pc = quad ^ (((c >> 3) ^ c) & 3);
      half8 b = *(const half8*)(fTw + (ct * 16 + mm) * 32 + pc * 8);
      floatx4 acc = __builtin_amdgcn_mfma_f32_16x16x32_f16(a0, b, fz, 0, 0, 0);
      uint fp = fx2s[pl][c];
      half8 b2 = {};
      b2[0] = __builtin_bit_cast(_Float16, (unsigned short)(fp & 0xffffu));
      b2[1] = __builtin_bit_cast(_Float16, (unsigned short)(fp >> 16));
      acc = __builtin_amdgcn_mfma_f32_16x16x32_f16(a2, b2, acc, 0, 0, 0);
      half4 h = {(_Float16)acc[0], (_Float16)acc[1],
                 (_Float16)acc[2], (_Float16)acc[3]};
      if (ct == 0) *(half4*)(wfh + pl * 264 + mmw * 16 + quad * 4) = h;
      else         hq3[ct - 1] = h;
    }
  };

  // ---- write one held quarter (ct = idx+1) into wfh (row = mmw) ----
  auto write_hold = [&](const half4 (*hq)[3], int idx) {
    #pragma unroll
    for (int pp = 0; pp < 4; ++pp)
      *(half4*)(wfh + (wave * 4 + pp) * 264 + mmw * 16 + quad * 4) = hq[pp][idx];
  };

  // ---- quarter-K GEMM: 8 k-steps; coalesced B (1KB wave-load per k-step);
  //      setprio(1) keeps the MFMA burst fed (T5, independent-block regime) ----
  auto gemm_q = [&](const _Float16* bmat, int p, floatx4& A, floatx4& B) {
    const _Float16* brow = bmat + ((wave * 4 + p) * 8) * 512 + mm * 32 + quad * 8;
    const _Float16* arow = wfh + mm * 264;
    __builtin_amdgcn_s_setprio(1);
    #pragma unroll
    for (int k2 = 0; k2 < 8; ++k2) {
      half8 af = *(const half8*)(arow + k2 * 32 + quad * 8);
      half8 bf = *(const half8*)(brow + k2 * 512);
      if (k2 & 1) B = __builtin_amdgcn_mfma_f32_16x16x32_f16(af, bf, B, 0, 0, 0);
      else        A = __builtin_amdgcn_mfma_f32_16x16x32_f16(af, bf, A, 0, 0, 0);
    }
    __builtin_amdgcn_s_setprio(0);
  };

  uint4 G0[2], G1[2];       // single gather buffer (16 VGPRs)
  half4 hq[4][3];           // deferred quarters, packed f16 (12 VGPRs)
  const float k0x = kpts[me * 3 + 0], k0y = kpts[me * 3 + 1], k0z = kpts[me * 3 + 2];

  // ================= conv0 (rigid kernel points) =================
  {
    load_g(wave * 4, G0, G1);
    #pragma unroll
    for (int pp = 0; pp < 4; ++pp) {
      int pl = wave * 4 + pp;
      transpose_g(G0, G1);
      if (pp < 3) load_g(pl + 1, G0, G1);   // issue next gather; conv covers it
      conv_point(pl, k0x, k0y, k0z, 1.f, hq[pp]);
    }
  }
  load_g(wave * 4, G0, G1);   // prefetch conv1 p0 under GEMM0
  __syncthreads();

  // ================= GEMM0 (4 quarter phases) -> def_kp + modulations ========
  {
    floatx4 A = fz, B = fz;
    gemm_q(owt, 0, A, B);
    __syncthreads(); write_hold(hq, 0); __syncthreads();
    gemm_q(owt, 1, A, B);
    __syncthreads(); write_hold(hq, 1); __syncthreads();
    gemm_q(owt, 2, A, B);
    __syncthreads(); write_hold(hq, 2); __syncthreads();
    gemm_q(owt, 3, A, B);
    int d = wave * 16 + mm;
    float bv = (d < 60) ? obias[d] : 0.f;
    float kv = (d < 45) ? kpts[d] : 0.f;
    #pragma unroll
    for (int r = 0; r < 4; ++r) {
      int pt = quad * 4 + r;
      float v = A[r] + B[r] + bv;
      if (d < 60)
        dk[pt][d] = (d < 45) ? (kv + 0.5f * v)            // def_kp = kp + f0*EXTENT
                             : (2.f / (1.f + expf(-v)));  // modulation
    }
  }
  __syncthreads();   // dk ready; GEMM0 wfh reads done

  // ================= conv1 (deformed kernel points) =================
  #pragma unroll
  for (int pp = 0; pp < 4; ++pp) {
    int pl = wave * 4 + pp;
    float kx = dk[pl][me * 3 + 0], ky = dk[pl][me * 3 + 1], kz = dk[pl][me * 3 + 2];
    float modme = dk[pl][45 + me];
    transpose_g(G0, G1);
    if (pp < 3) load_g(pl + 1, G0, G1);
    conv_point(pl, kx, ky, kz, modme, hq[pp]);
  }
  __syncthreads();

  // ================= GEMM1 (4 quarter phases) -> x + fused batch stats =======
  {
    floatx4 A = fz, B = fz;
    gemm_q(wt, 0, A, B);
    __syncthreads(); write_hold(hq, 0); __syncthreads();
    gemm_q(wt, 1, A, B);
    __syncthreads(); write_hold(hq, 1); __syncthreads();
    gemm_q(wt, 2, A, B);
    __syncthreads(); write_hold(hq, 2); __syncthreads();
    gemm_q(wt, 3, A, B);
    int d = wave * 16 + mm;
    float s1 = 0.f, s2 = 0.f;
    #pragma unroll
    for (int r = 0; r < 4; ++r) {
      float v = A[r] + B[r];
      outx[(base + quad * 4 + r) * 64 + d] = v;
      s1 += v; s2 += v * v;
    }
    s1 += __shfl_xor(s1, 16); s2 += __shfl_xor(s2, 16);
    s1 += __shfl_xor(s1, 32); s2 += __shfl_xor(s2, 32);
    if (lane < 16) {
      atomicAdd(&stats[d], s1);
      atomicAdd(&stats[64 + d], s2);
    }
  }
}

// ---------------------------------------------------------------------------
// BN (batch stats, biased var, eps=1e-6) + LeakyReLU(0.1), in-place
// ---------------------------------------------------------------------------
__global__ __launch_bounds__(256) void k_norm(
    float* __restrict__ x, const float* __restrict__ stats,
    const float* __restrict__ gamma, const float* __restrict__ beta)
{
  const int i = blockIdx.x * 256 + threadIdx.x;
  float4 v = ((float4*)x)[i];
  const int c0 = (i * 4) & 63;
  float o[4] = {v.x, v.y, v.z, v.w};
  #pragma unroll
  for (int j = 0; j < 4; ++j) {
    int c = c0 + j;
    float mean = stats[c] * (1.f / NPTS);
    float var  = stats[64 + c] * (1.f / NPTS) - mean * mean;
    float s = rsqrtf(var + 1e-6f) * gamma[c];
    float y = (o[j] - mean) * s + beta[c];
    o[j] = (y >= 0.f) ? y : 0.1f * y;
  }
  float4 rv = {o[0], o[1], o[2], o[3]};
  ((float4*)x)[i] = rv;
}

// ---------------------------------------------------------------------------
extern "C" void kernel_launch(void* const* d_in, const int* in_sizes, int n_in,
                              void* d_out, int out_size, void* d_ws, size_t ws_size,
                              hipStream_t stream)
{
  const float* query   = (const float*)d_in[0];
  const float* support = (const float*)d_in[1];
  const int*   nidx    = (const int*)d_in[2];
  const float* feat    = (const float*)d_in[3];
  const float* weight  = (const float*)d_in[4];
  const float* oweight = (const float*)d_in[5];
  const float* obias   = (const float*)d_in[6];
  const float* gamma   = (const float*)d_in[7];
  const float* beta    = (const float*)d_in[8];
  const float* kpts    = (const float*)d_in[9];
  float* x = (float*)d_out;

  char* ws = (char*)d_ws;
  _Float16* featH = (_Float16*)ws;                  // 8,388,608 B
  _Float16* owt   = (_Float16*)(ws + 8388608);      //   131,072 B
  _Float16* wt    = (_Float16*)(ws + 8519680);      //   131,072 B
  float*    stats = (float*)(ws + 8650752);         //       512 B

  k_prep<<<4160, 256, 0, stream>>>(oweight, weight, feat, owt, wt, featH, stats);
  k_fused<<<4096, 256, 0, stream>>>(query, support, nidx, featH, kpts, obias,
                                    owt, wt, x, stats);
  k_norm<<<4096, 256, 0, stream>>>(x, stats, gamma, beta);
}